// Round 10
// baseline (118.526 us; speedup 1.0000x reference)
//
#include <hip/hip_runtime.h>

typedef float f32x4 __attribute__((ext_vector_type(4)));
typedef short short8 __attribute__((ext_vector_type(8)));

#define NTYPES 4

// ws layout (bytes):
//   [0,64)        meta ints: 0-3 counts, 4-7 cursors, 8-12 bases (bases[i]=meta[8+i])
//   [512,1024)    dump row (pad-node store sink)
//   [1024,...)    perm[ntiles*64] ints (pad slots = -1)
//   [402432,)     W1T bf16 [4][256][128]  W1T[t][hcol][k]
//   [664576,)     W2T bf16 [4][128][256]  W2T[t][ocol][h]

static __device__ __forceinline__ unsigned short f2bf(float f) {
  union { float f; unsigned int u; } v; v.f = f;
  unsigned int u = v.u;
  unsigned int r = u + 0x7FFFu + ((u >> 16) & 1u);   // round-nearest-even
  return (unsigned short)(r >> 16);
}

#define LGKM_BAR() do { \
  asm volatile("s_waitcnt lgkmcnt(0)" ::: "memory"); \
  __builtin_amdgcn_s_barrier(); \
  __builtin_amdgcn_sched_barrier(0); } while (0)

// Coalesced 64x64 LDS-tiled transpose+cast for W1->W1T, W2->W2T.
// Block 0 also zeroes meta. Grid = 64 blocks: 0-31 W1 tiles, 32-63 W2 tiles.
__global__ __launch_bounds__(256) void k_prep(const float* __restrict__ W1,
                                              const float* __restrict__ W2,
                                              unsigned short* __restrict__ W1T,
                                              unsigned short* __restrict__ W2T,
                                              int* __restrict__ meta) {
  __shared__ unsigned short s[64][72];   // +8 pad: transpose-read conflicts
  const int tid = threadIdx.x;
  const int b = blockIdx.x;
  if (b == 0 && tid < 16) meta[tid] = 0;
  const int bb = b & 31;
  const int t = bb >> 3, ti = bb & 7;    // type, tile within type
  const float* src; unsigned short* dst; int scols, tr, tc;
  if (b < 32) { src = W1 + t * 32768; dst = W1T + t * 32768; scols = 256; tr = ti >> 2; tc = ti & 3; }
  else        { src = W2 + t * 32768; dst = W2T + t * 32768; scols = 128; tr = ti >> 1; tc = ti & 1; }
  const int srows = 32768 / scols;       // dst row length
  const int r0 = tid >> 4, c4 = (tid & 15) << 2;
  #pragma unroll
  for (int i = 0; i < 4; ++i) {
    int r = tr * 64 + i * 16 + r0;
    float4 v = *(const float4*)(src + r * scols + tc * 64 + c4);
    s[i * 16 + r0][c4 + 0] = f2bf(v.x);
    s[i * 16 + r0][c4 + 1] = f2bf(v.y);
    s[i * 16 + r0][c4 + 2] = f2bf(v.z);
    s[i * 16 + r0][c4 + 3] = f2bf(v.w);
  }
  __syncthreads();
  #pragma unroll
  for (int i = 0; i < 4; ++i) {
    int orow = i * 16 + r0;              // local dst row (= src col)
    ushort4 u;
    u.x = s[c4 + 0][orow];
    u.y = s[c4 + 1][orow];
    u.z = s[c4 + 2][orow];
    u.w = s[c4 + 3][orow];
    *(ushort4*)(dst + (tc * 64 + orow) * srows + tr * 64 + c4) = u;
  }
}

__global__ __launch_bounds__(256) void k_hist(const int* __restrict__ NT, int n,
                                              int* __restrict__ meta) {
  __shared__ int c[NTYPES];
  if (threadIdx.x < NTYPES) c[threadIdx.x] = 0;
  __syncthreads();
  int i = blockIdx.x * 256 + threadIdx.x;
  if (i < n) atomicAdd(&c[NT[i]], 1);
  __syncthreads();
  if (threadIdx.x < NTYPES && c[threadIdx.x] > 0)
    atomicAdd(&meta[threadIdx.x], c[threadIdx.x]);
}

// scatter + inline prefix (from final counts) + base publish + pad fill
__global__ __launch_bounds__(256) void k_scatter(const int* __restrict__ NT, int n,
                                                 int* __restrict__ meta,
                                                 int* __restrict__ perm) {
  __shared__ int cnt[NTYPES];
  __shared__ int cbase[NTYPES];
  __shared__ int sb[NTYPES + 1];
  if (threadIdx.x < NTYPES) cnt[threadIdx.x] = 0;
  if (threadIdx.x == 0) {
    int b = 0; sb[0] = 0;
    for (int t = 0; t < NTYPES; ++t) {
      b += (meta[t] + 63) & ~63;           // pad each segment to 64
      sb[t + 1] = b;
    }
  }
  __syncthreads();
  int i = blockIdx.x * 256 + threadIdx.x;
  int t = 0, r = 0;
  bool valid = (i < n);
  if (valid) { t = NT[i]; r = atomicAdd(&cnt[t], 1); }
  __syncthreads();
  if (threadIdx.x < NTYPES)
    cbase[threadIdx.x] = atomicAdd(&meta[4 + threadIdx.x], cnt[threadIdx.x]);
  __syncthreads();
  if (valid) perm[sb[t] + cbase[t] + r] = i;
  if (blockIdx.x == 0) {
    if (threadIdx.x <= NTYPES) meta[8 + threadIdx.x] = sb[threadIdx.x];
    int tt = threadIdx.x >> 6, j = threadIdx.x & 63;   // pad count per type <= 63
    int p = sb[tt] + meta[tt] + j;
    if (p < sb[tt + 1]) perm[p] = -1;
  }
}

// Weights-stationary persistent MLP, 4 waves (256 thr), 64-node tile.
// Wave w: ALL 64 nodes x hcols [w*64,+64) (L1) / ocols [w*32,+32) (L2).
// vs the 8-wave col-split: halves redundant LDS B-frag reads (8x -> 4x).
// 2 barriers/tile, single-buffered LDS (WAR safe via barrier ordering).
// Direct f32x4 global stores from acc2 (L2 write-combines rows).
// Swizzle ^(row&7)<<4 chosen so read class bits = (lo&7)^hi -> even 8
// lanes/16B-class (the old pattern collapsed to 8-way same-bank-quad).
__global__ __launch_bounds__(256, 2) void k_mlpw(
    const float* __restrict__ X, const int* __restrict__ perm,
    const int* __restrict__ meta,
    const unsigned short* __restrict__ W1T, const unsigned short* __restrict__ W2T,
    const float* __restrict__ B1, const float* __restrict__ B2,
    float* __restrict__ OUT, float* __restrict__ dump) {
  __shared__ __align__(16) unsigned char x_lds[16384];   // 64 x 128 bf16 (swizzled)
  __shared__ __align__(16) unsigned char h_lds[32768];   // 64 x 256 bf16 (swizzled)

  const int tid = threadIdx.x;
  const int l  = tid & 63, w = tid >> 6;   // wave 0..3
  const int lo = l & 15,  hi = l >> 4;

  const int t  = blockIdx.x >> 7;          // 128 blocks per type
  const int lb = blockIdx.x & 127;
  const int g0 = meta[8 + t] >> 6;         // first tile of this type
  const int g1 = meta[9 + t] >> 6;         // one past last
  const int nt = g1 - g0 - lb;
  if (nt <= 0) return;
  const int cnt = (nt + 127) >> 7;

  const int gr = tid >> 2;           // gather row 0..63
  const int gq = tid & 3;            // 32-float column group

  // ---- prologue: gather tile 0 (128B/lane, contiguous) ----
  int pm = perm[(g0 + lb) * 64 + gr];
  float4 xv[8];
  #pragma unroll
  for (int i = 0; i < 8; ++i) xv[i] = make_float4(0.f, 0.f, 0.f, 0.f);
  if (pm >= 0) {
    const float4* s = (const float4*)(X + (size_t)pm * 128 + gq * 32);
    #pragma unroll
    for (int i = 0; i < 8; ++i) xv[i] = s[i];
  }

  // ---- weights + biases into registers, once per block ----
  const unsigned short* w1t = W1T + (t << 15);
  const unsigned short* w2t = W2T + (t << 15);
  short8 a1[4][4];                   // [ks][hfrag m] : 64 VGPR
  #pragma unroll
  for (int ks = 0; ks < 4; ++ks)
    #pragma unroll
    for (int m = 0; m < 4; ++m)
      a1[ks][m] = *(const short8*)(w1t + (w * 64 + m * 16 + lo) * 128 + ks * 32 + hi * 8);
  short8 a2[8][2];                   // [ks][ofrag mo] : 64 VGPR
  #pragma unroll
  for (int ks = 0; ks < 8; ++ks)
    #pragma unroll
    for (int mo = 0; mo < 2; ++mo)
      a2[ks][mo] = *(const short8*)(w2t + (w * 32 + mo * 16 + lo) * 256 + ks * 32 + hi * 8);
  f32x4 bb1[4], bb2[2];
  #pragma unroll
  for (int m = 0; m < 4; ++m)
    bb1[m] = *(const f32x4*)(B1 + t * 256 + w * 64 + m * 16 + hi * 4);
  #pragma unroll
  for (int mo = 0; mo < 2; ++mo)
    bb2[mo] = *(const f32x4*)(B2 + t * 128 + w * 32 + mo * 16 + hi * 4);

  for (int j = 0; j < cnt; ++j) {
    const int g = g0 + lb + j * 128;
    const bool hn = (j + 1 < cnt);

    // ---- x regs -> bf16 swizzled LDS (4 x ds_write_b128/lane) ----
    {
      const int rbase = gr * 256;
      const int swz = (gr & 7) << 4;
      #pragma unroll
      for (int q = 0; q < 4; ++q) {
        short8 c;
        float4 va = xv[2 * q], vb = xv[2 * q + 1];
        c[0] = (short)f2bf(va.x); c[1] = (short)f2bf(va.y);
        c[2] = (short)f2bf(va.z); c[3] = (short)f2bf(va.w);
        c[4] = (short)f2bf(vb.x); c[5] = (short)f2bf(vb.y);
        c[6] = (short)f2bf(vb.z); c[7] = (short)f2bf(vb.w);
        int byte = (rbase + gq * 64 + q * 16) ^ swz;
        *(short8*)(x_lds + byte) = c;
      }
    }
    LGKM_BAR();   // x tile visible (also: all h reads of tile j-1 retired)

    // prefetch next tile's perm + this tile's store rowids (latency hides under L1)
    int pmn = -1;
    if (hn) pmn = perm[(g + 128) * 64 + gr];
    int rid[4];
    #pragma unroll
    for (int n = 0; n < 4; ++n) rid[n] = perm[g * 64 + n * 16 + lo];

    // ---- layer 1: W1 frags in regs (A), x from LDS (B) ----
    f32x4 acc[4][4];   // [hfrag m][nodefrag n]
    #pragma unroll
    for (int m = 0; m < 4; ++m)
      #pragma unroll
      for (int n = 0; n < 4; ++n) acc[m][n] = (f32x4){0.f, 0.f, 0.f, 0.f};
    #pragma unroll
    for (int ks = 0; ks < 4; ++ks) {
      short8 b[4];
      #pragma unroll
      for (int n = 0; n < 4; ++n) {
        int row = n * 16 + lo;
        int byte = (row * 256 + ks * 64 + hi * 16) ^ ((row & 7) << 4);
        b[n] = *(const short8*)(x_lds + byte);
      }
      #pragma unroll
      for (int m = 0; m < 4; ++m)
        #pragma unroll
        for (int n = 0; n < 4; ++n)
          acc[m][n] = __builtin_amdgcn_mfma_f32_16x16x32_bf16(a1[ks][m], b[n], acc[m][n], 0, 0, 0);
    }

    // bias + relu -> h LDS. C layout: lane holds node n*16+lo, 4 consecutive
    // hcols (w*64 + m*16 + hi*4 + r) -> one ushort4 per (m,n)
    #pragma unroll
    for (int m = 0; m < 4; ++m) {
      const int hw2 = w * 128 + m * 32 + hi * 8;   // hcol*2 byte offset
      #pragma unroll
      for (int n = 0; n < 4; ++n) {
        int node = n * 16 + lo;
        ushort4 hv;
        hv.x = f2bf(fmaxf(acc[m][n][0] + bb1[m][0], 0.f));
        hv.y = f2bf(fmaxf(acc[m][n][1] + bb1[m][1], 0.f));
        hv.z = f2bf(fmaxf(acc[m][n][2] + bb1[m][2], 0.f));
        hv.w = f2bf(fmaxf(acc[m][n][3] + bb1[m][3], 0.f));
        int byte = (node * 512 + hw2) ^ ((node & 7) << 4);
        *(ushort4*)(h_lds + byte) = hv;
      }
    }
    LGKM_BAR();   // h visible (x reads retired -> next x-write safe)

    // issue next tile's X gather: hides under layer 2 + stores
    float4 nv[8];
    #pragma unroll
    for (int i = 0; i < 8; ++i) nv[i] = make_float4(0.f, 0.f, 0.f, 0.f);
    if (pmn >= 0) {
      const float4* s = (const float4*)(X + (size_t)pmn * 128 + gq * 32);
      #pragma unroll
      for (int i = 0; i < 8; ++i) nv[i] = s[i];
    }

    // ---- layer 2: W2 frags in regs (A), h from LDS (B) ----
    f32x4 acc2[2][4];   // [ofrag mo][nodefrag n]
    #pragma unroll
    for (int mo = 0; mo < 2; ++mo)
      #pragma unroll
      for (int n = 0; n < 4; ++n) acc2[mo][n] = (f32x4){0.f, 0.f, 0.f, 0.f};
    #pragma unroll
    for (int ks = 0; ks < 8; ++ks) {
      short8 b[4];
      #pragma unroll
      for (int n = 0; n < 4; ++n) {
        int node = n * 16 + lo;
        int byte = (node * 512 + ks * 64 + hi * 16) ^ ((node & 7) << 4);
        b[n] = *(const short8*)(h_lds + byte);
      }
      #pragma unroll
      for (int mo = 0; mo < 2; ++mo)
        #pragma unroll
        for (int n = 0; n < 4; ++n)
          acc2[mo][n] = __builtin_amdgcn_mfma_f32_16x16x32_bf16(a2[ks][mo], b[n], acc2[mo][n], 0, 0, 0);
    }

    // direct store: lane holds node n*16+lo, 4 consecutive ocols -> f32x4
    #pragma unroll
    for (int mo = 0; mo < 2; ++mo) {
      const int oc = w * 32 + mo * 16 + hi * 4;
      #pragma unroll
      for (int n = 0; n < 4; ++n) {
        f32x4 o = acc2[mo][n];
        o[0] += bb2[mo][0]; o[1] += bb2[mo][1];
        o[2] += bb2[mo][2]; o[3] += bb2[mo][3];
        float* dst = (rid[n] >= 0) ? (OUT + (size_t)rid[n] * 128 + oc) : (dump + oc);
        *(f32x4*)dst = o;
      }
    }
    // stores + next gather stay in flight across the loop-back barrier

    #pragma unroll
    for (int i = 0; i < 8; ++i) xv[i] = nv[i];
  }
}

extern "C" void kernel_launch(void* const* d_in, const int* in_sizes, int n_in,
                              void* d_out, int out_size, void* d_ws, size_t ws_size,
                              hipStream_t stream) {
  const float* X  = (const float*)d_in[0];
  const int*   NT = (const int*)d_in[1];
  const float* W1 = (const float*)d_in[2];
  const float* B1 = (const float*)d_in[3];
  const float* W2 = (const float*)d_in[4];
  const float* B2 = (const float*)d_in[5];
  float* OUT = (float*)d_out;
  const int n = in_sizes[1];

  char* ws = (char*)d_ws;
  int* meta = (int*)ws;                                   // counts/cursors/bases
  float* dump = (float*)(ws + 512);
  int* perm = (int*)(ws + 1024);
  unsigned short* W1T = (unsigned short*)(ws + 402432);
  unsigned short* W2T = (unsigned short*)(ws + 664576);

  k_prep<<<64, 256, 0, stream>>>(W1, W2, W1T, W2T, meta);
  const int nb = (n + 255) / 256;
  k_hist<<<nb, 256, 0, stream>>>(NT, n, meta);
  k_scatter<<<nb, 256, 0, stream>>>(NT, n, meta, perm);
  k_mlpw<<<512, 256, 0, stream>>>(X, perm, meta, W1T, W2T, B1, B2, OUT, dump);
}

// Round 11
// 58.337 us; speedup vs baseline: 2.0317x; 2.0317x over previous
//
#include <hip/hip_runtime.h>

typedef float f32x4 __attribute__((ext_vector_type(4)));
typedef short short8 __attribute__((ext_vector_type(8)));

#define NTYPES 4

// ws layout (bytes):
//   [0,64)        meta ints: 0-3 counts, 4-7 cursors, 8-12 bases (bases[i]=meta[8+i])
//   [512,1024)    dump row (pad-node store sink)
//   [1024,...)    perm[ntiles*64] ints (pad slots = -1)
//   [402432,)     W1T bf16 [4][256][128]  W1T[t][hcol][k]
//   [664576,)     W2T bf16 [4][128][256]  W2T[t][ocol][h]

static __device__ __forceinline__ unsigned short f2bf(float f) {
  union { float f; unsigned int u; } v; v.f = f;
  unsigned int u = v.u;
  unsigned int r = u + 0x7FFFu + ((u >> 16) & 1u);   // round-nearest-even
  return (unsigned short)(r >> 16);
}

#define LGKM_BAR() do { \
  asm volatile("s_waitcnt lgkmcnt(0)" ::: "memory"); \
  __builtin_amdgcn_s_barrier(); \
  __builtin_amdgcn_sched_barrier(0); } while (0)

// Coalesced 64x64 LDS-tiled transpose+cast for W1->W1T, W2->W2T.
// Block 0 also zeroes meta. Grid = 64 blocks: 0-31 W1 tiles, 32-63 W2 tiles.
__global__ __launch_bounds__(256) void k_prep(const float* __restrict__ W1,
                                              const float* __restrict__ W2,
                                              unsigned short* __restrict__ W1T,
                                              unsigned short* __restrict__ W2T,
                                              int* __restrict__ meta) {
  __shared__ unsigned short s[64][72];   // +8 pad: transpose-read conflicts
  const int tid = threadIdx.x;
  const int b = blockIdx.x;
  if (b == 0 && tid < 16) meta[tid] = 0;
  const int bb = b & 31;
  const int t = bb >> 3, ti = bb & 7;    // type, tile within type
  const float* src; unsigned short* dst; int scols, tr, tc;
  if (b < 32) { src = W1 + t * 32768; dst = W1T + t * 32768; scols = 256; tr = ti >> 2; tc = ti & 3; }
  else        { src = W2 + t * 32768; dst = W2T + t * 32768; scols = 128; tr = ti >> 1; tc = ti & 1; }
  const int srows = 32768 / scols;       // dst row length
  const int r0 = tid >> 4, c4 = (tid & 15) << 2;
  #pragma unroll
  for (int i = 0; i < 4; ++i) {
    int r = tr * 64 + i * 16 + r0;
    float4 v = *(const float4*)(src + r * scols + tc * 64 + c4);
    s[i * 16 + r0][c4 + 0] = f2bf(v.x);
    s[i * 16 + r0][c4 + 1] = f2bf(v.y);
    s[i * 16 + r0][c4 + 2] = f2bf(v.z);
    s[i * 16 + r0][c4 + 3] = f2bf(v.w);
  }
  __syncthreads();
  #pragma unroll
  for (int i = 0; i < 4; ++i) {
    int orow = i * 16 + r0;              // local dst row (= src col)
    ushort4 u;
    u.x = s[c4 + 0][orow];
    u.y = s[c4 + 1][orow];
    u.z = s[c4 + 2][orow];
    u.w = s[c4 + 3][orow];
    *(ushort4*)(dst + (tc * 64 + orow) * srows + tr * 64 + c4) = u;
  }
}

__global__ __launch_bounds__(256) void k_hist(const int* __restrict__ NT, int n,
                                              int* __restrict__ meta) {
  __shared__ int c[NTYPES];
  if (threadIdx.x < NTYPES) c[threadIdx.x] = 0;
  __syncthreads();
  int i = blockIdx.x * 256 + threadIdx.x;
  if (i < n) atomicAdd(&c[NT[i]], 1);
  __syncthreads();
  if (threadIdx.x < NTYPES && c[threadIdx.x] > 0)
    atomicAdd(&meta[threadIdx.x], c[threadIdx.x]);
}

// scatter + inline prefix (from final counts) + base publish + pad fill
__global__ __launch_bounds__(256) void k_scatter(const int* __restrict__ NT, int n,
                                                 int* __restrict__ meta,
                                                 int* __restrict__ perm) {
  __shared__ int cnt[NTYPES];
  __shared__ int cbase[NTYPES];
  __shared__ int sb[NTYPES + 1];
  if (threadIdx.x < NTYPES) cnt[threadIdx.x] = 0;
  if (threadIdx.x == 0) {
    int b = 0; sb[0] = 0;
    for (int t = 0; t < NTYPES; ++t) {
      b += (meta[t] + 63) & ~63;           // pad each segment to 64
      sb[t + 1] = b;
    }
  }
  __syncthreads();
  int i = blockIdx.x * 256 + threadIdx.x;
  int t = 0, r = 0;
  bool valid = (i < n);
  if (valid) { t = NT[i]; r = atomicAdd(&cnt[t], 1); }
  __syncthreads();
  if (threadIdx.x < NTYPES)
    cbase[threadIdx.x] = atomicAdd(&meta[4 + threadIdx.x], cnt[threadIdx.x]);
  __syncthreads();
  if (valid) perm[sb[t] + cbase[t] + r] = i;
  if (blockIdx.x == 0) {
    if (threadIdx.x <= NTYPES) meta[8 + threadIdx.x] = sb[threadIdx.x];
    int tt = threadIdx.x >> 6, j = threadIdx.x & 63;   // pad count per type <= 63
    int p = sb[tt] + meta[tt] + j;
    if (p < sb[tt + 1]) perm[p] = -1;
  }
}

// Weights-stationary persistent MLP, 4 waves (256 thr), 64-node tile.
// Wave w: ALL 64 nodes x hcols [w*64,+64) (L1) / ocols [w*32,+32) (L2).
// Halves redundant LDS B-frag reads vs 8-wave col-split (8x -> 4x): the
// LDS pipe is the serialized per-CU resource (R9 analysis, R10 verified
// correct). VGPR demand ~260 -> __launch_bounds__(256, 1): cap 512, no
// spill (m08: clean through 450). (256,2) capped 256 and the allocator
// collapsed to 128 + scratch spill: +69MB FETCH (round-10 regression).
// Grid 256 = one persistent block per CU, 64 blocks/type, tile stride 64.
__global__ __launch_bounds__(256, 1) void k_mlpw(
    const float* __restrict__ X, const int* __restrict__ perm,
    const int* __restrict__ meta,
    const unsigned short* __restrict__ W1T, const unsigned short* __restrict__ W2T,
    const float* __restrict__ B1, const float* __restrict__ B2,
    float* __restrict__ OUT, float* __restrict__ dump) {
  __shared__ __align__(16) unsigned char x_lds[16384];   // 64 x 128 bf16 (swizzled)
  __shared__ __align__(16) unsigned char h_lds[32768];   // 64 x 256 bf16 (swizzled)

  const int tid = threadIdx.x;
  const int l  = tid & 63, w = tid >> 6;   // wave 0..3
  const int lo = l & 15,  hi = l >> 4;

  const int t  = blockIdx.x >> 6;          // 64 blocks per type
  const int lb = blockIdx.x & 63;
  const int g0 = meta[8 + t] >> 6;         // first tile of this type
  const int g1 = meta[9 + t] >> 6;         // one past last
  const int nt = g1 - g0 - lb;
  if (nt <= 0) return;
  const int cnt = (nt + 63) >> 6;

  const int gr = tid >> 2;           // gather row 0..63
  const int gq = tid & 3;            // 32-float column group

  // ---- prologue: gather tile 0 (128B/lane, contiguous) ----
  int pm = perm[(g0 + lb) * 64 + gr];
  float4 xv[8];
  #pragma unroll
  for (int i = 0; i < 8; ++i) xv[i] = make_float4(0.f, 0.f, 0.f, 0.f);
  if (pm >= 0) {
    const float4* s = (const float4*)(X + (size_t)pm * 128 + gq * 32);
    #pragma unroll
    for (int i = 0; i < 8; ++i) xv[i] = s[i];
  }

  // ---- weights + biases into registers, once per block ----
  const unsigned short* w1t = W1T + (t << 15);
  const unsigned short* w2t = W2T + (t << 15);
  short8 a1[4][4];                   // [ks][hfrag m] : 64 VGPR
  #pragma unroll
  for (int ks = 0; ks < 4; ++ks)
    #pragma unroll
    for (int m = 0; m < 4; ++m)
      a1[ks][m] = *(const short8*)(w1t + (w * 64 + m * 16 + lo) * 128 + ks * 32 + hi * 8);
  short8 a2[8][2];                   // [ks][ofrag mo] : 64 VGPR
  #pragma unroll
  for (int ks = 0; ks < 8; ++ks)
    #pragma unroll
    for (int mo = 0; mo < 2; ++mo)
      a2[ks][mo] = *(const short8*)(w2t + (w * 32 + mo * 16 + lo) * 256 + ks * 32 + hi * 8);
  f32x4 bb1[4], bb2[2];
  #pragma unroll
  for (int m = 0; m < 4; ++m)
    bb1[m] = *(const f32x4*)(B1 + t * 256 + w * 64 + m * 16 + hi * 4);
  #pragma unroll
  for (int mo = 0; mo < 2; ++mo)
    bb2[mo] = *(const f32x4*)(B2 + t * 128 + w * 32 + mo * 16 + hi * 4);

  for (int j = 0; j < cnt; ++j) {
    const int g = g0 + lb + j * 64;
    const bool hn = (j + 1 < cnt);

    // ---- x regs -> bf16 swizzled LDS (4 x ds_write_b128/lane) ----
    {
      const int rbase = gr * 256;
      const int swz = (gr & 7) << 4;
      #pragma unroll
      for (int q = 0; q < 4; ++q) {
        short8 c;
        float4 va = xv[2 * q], vb = xv[2 * q + 1];
        c[0] = (short)f2bf(va.x); c[1] = (short)f2bf(va.y);
        c[2] = (short)f2bf(va.z); c[3] = (short)f2bf(va.w);
        c[4] = (short)f2bf(vb.x); c[5] = (short)f2bf(vb.y);
        c[6] = (short)f2bf(vb.z); c[7] = (short)f2bf(vb.w);
        int byte = (rbase + gq * 64 + q * 16) ^ swz;
        *(short8*)(x_lds + byte) = c;
      }
    }
    LGKM_BAR();   // x tile visible (also: all h reads of tile j-1 retired)

    // prefetch next tile's perm + this tile's store rowids (latency hides under L1)
    int pmn = -1;
    if (hn) pmn = perm[(g + 64) * 64 + gr];
    int rid[4];
    #pragma unroll
    for (int n = 0; n < 4; ++n) rid[n] = perm[g * 64 + n * 16 + lo];

    // ---- layer 1: W1 frags in regs (A), x from LDS (B) ----
    f32x4 acc[4][4];   // [hfrag m][nodefrag n]
    #pragma unroll
    for (int m = 0; m < 4; ++m)
      #pragma unroll
      for (int n = 0; n < 4; ++n) acc[m][n] = (f32x4){0.f, 0.f, 0.f, 0.f};
    #pragma unroll
    for (int ks = 0; ks < 4; ++ks) {
      short8 b[4];
      #pragma unroll
      for (int n = 0; n < 4; ++n) {
        int row = n * 16 + lo;
        int byte = (row * 256 + ks * 64 + hi * 16) ^ ((row & 7) << 4);
        b[n] = *(const short8*)(x_lds + byte);
      }
      #pragma unroll
      for (int m = 0; m < 4; ++m)
        #pragma unroll
        for (int n = 0; n < 4; ++n)
          acc[m][n] = __builtin_amdgcn_mfma_f32_16x16x32_bf16(a1[ks][m], b[n], acc[m][n], 0, 0, 0);
    }

    // bias + relu -> h LDS. C layout: lane holds node n*16+lo, 4 consecutive
    // hcols (w*64 + m*16 + hi*4 + r) -> one ushort4 per (m,n)
    #pragma unroll
    for (int m = 0; m < 4; ++m) {
      const int hw2 = w * 128 + m * 32 + hi * 8;   // hcol*2 byte offset
      #pragma unroll
      for (int n = 0; n < 4; ++n) {
        int node = n * 16 + lo;
        ushort4 hv;
        hv.x = f2bf(fmaxf(acc[m][n][0] + bb1[m][0], 0.f));
        hv.y = f2bf(fmaxf(acc[m][n][1] + bb1[m][1], 0.f));
        hv.z = f2bf(fmaxf(acc[m][n][2] + bb1[m][2], 0.f));
        hv.w = f2bf(fmaxf(acc[m][n][3] + bb1[m][3], 0.f));
        int byte = (node * 512 + hw2) ^ ((node & 7) << 4);
        *(ushort4*)(h_lds + byte) = hv;
      }
    }
    LGKM_BAR();   // h visible (x reads retired -> next x-write safe)

    // issue next tile's X gather: hides under layer 2 + stores
    float4 nv[8];
    #pragma unroll
    for (int i = 0; i < 8; ++i) nv[i] = make_float4(0.f, 0.f, 0.f, 0.f);
    if (pmn >= 0) {
      const float4* s = (const float4*)(X + (size_t)pmn * 128 + gq * 32);
      #pragma unroll
      for (int i = 0; i < 8; ++i) nv[i] = s[i];
    }

    // ---- layer 2: W2 frags in regs (A), h from LDS (B) ----
    f32x4 acc2[2][4];   // [ofrag mo][nodefrag n]
    #pragma unroll
    for (int mo = 0; mo < 2; ++mo)
      #pragma unroll
      for (int n = 0; n < 4; ++n) acc2[mo][n] = (f32x4){0.f, 0.f, 0.f, 0.f};
    #pragma unroll
    for (int ks = 0; ks < 8; ++ks) {
      short8 b[4];
      #pragma unroll
      for (int n = 0; n < 4; ++n) {
        int node = n * 16 + lo;
        int byte = (node * 512 + ks * 64 + hi * 16) ^ ((node & 7) << 4);
        b[n] = *(const short8*)(h_lds + byte);
      }
      #pragma unroll
      for (int mo = 0; mo < 2; ++mo)
        #pragma unroll
        for (int n = 0; n < 4; ++n)
          acc2[mo][n] = __builtin_amdgcn_mfma_f32_16x16x32_bf16(a2[ks][mo], b[n], acc2[mo][n], 0, 0, 0);
    }

    // direct store: lane holds node n*16+lo, 4 consecutive ocols -> f32x4
    #pragma unroll
    for (int mo = 0; mo < 2; ++mo) {
      const int oc = w * 32 + mo * 16 + hi * 4;
      #pragma unroll
      for (int n = 0; n < 4; ++n) {
        f32x4 o = acc2[mo][n];
        o[0] += bb2[mo][0]; o[1] += bb2[mo][1];
        o[2] += bb2[mo][2]; o[3] += bb2[mo][3];
        float* dst = (rid[n] >= 0) ? (OUT + (size_t)rid[n] * 128 + oc) : (dump + oc);
        *(f32x4*)dst = o;
      }
    }
    // stores + next gather stay in flight across the loop-back barrier

    #pragma unroll
    for (int i = 0; i < 8; ++i) xv[i] = nv[i];
  }
}

extern "C" void kernel_launch(void* const* d_in, const int* in_sizes, int n_in,
                              void* d_out, int out_size, void* d_ws, size_t ws_size,
                              hipStream_t stream) {
  const float* X  = (const float*)d_in[0];
  const int*   NT = (const int*)d_in[1];
  const float* W1 = (const float*)d_in[2];
  const float* B1 = (const float*)d_in[3];
  const float* W2 = (const float*)d_in[4];
  const float* B2 = (const float*)d_in[5];
  float* OUT = (float*)d_out;
  const int n = in_sizes[1];

  char* ws = (char*)d_ws;
  int* meta = (int*)ws;                                   // counts/cursors/bases
  float* dump = (float*)(ws + 512);
  int* perm = (int*)(ws + 1024);
  unsigned short* W1T = (unsigned short*)(ws + 402432);
  unsigned short* W2T = (unsigned short*)(ws + 664576);

  k_prep<<<64, 256, 0, stream>>>(W1, W2, W1T, W2T, meta);
  const int nb = (n + 255) / 256;
  k_hist<<<nb, 256, 0, stream>>>(NT, n, meta);
  k_scatter<<<nb, 256, 0, stream>>>(NT, n, meta, perm);
  k_mlpw<<<256, 256, 0, stream>>>(X, perm, meta, W1T, W2T, B1, B2, OUT, dump);
}